// Round 8
// baseline (656.695 us; speedup 1.0000x reference)
//
#include <hip/hip_runtime.h>

#define DIN 128
#define DOUT 128

typedef float f4 __attribute__((ext_vector_type(4)));
typedef float f32x4 __attribute__((ext_vector_type(4)));
typedef short bf16x8 __attribute__((ext_vector_type(8)));
typedef unsigned short u16x8 __attribute__((ext_vector_type(8)));

__device__ inline unsigned short f2bf(float f) {
    unsigned u = __float_as_uint(f);
    u += 0x7FFFu + ((u >> 16) & 1u);   // round-to-nearest-even
    return (unsigned short)(u >> 16);
}

// Build Wt[m][dout][din] bf16 from W[r][din][dout] (m=0..3) and Wl[din][dout] (m=4).
__global__ void prep_w(const float* __restrict__ W, const float* __restrict__ Wl,
                       unsigned short* __restrict__ Wt, int total) {
    int id = blockIdx.x * 256 + threadIdx.x;
    if (id >= total) return;
    int m    = id >> 14;
    int rem  = id & 16383;
    int din  = rem >> 7;
    int dout = rem & 127;
    float v = (m < 4) ? W[(m << 14) + din * DOUT + dout] : Wl[din * DOUT + dout];
    Wt[(m << 14) + dout * DIN + din] = f2bf(v);
}

__global__ void deg_count(const int* __restrict__ dst, int* __restrict__ cnt,
                          int E, int N, int total) {
    int i = blockIdx.x * 256 + threadIdx.x;
    if (i >= total) return;
    int r = i / E;
    atomicAdd(&cnt[r * N + dst[i]], 1);
}

// ---- 3-pass exclusive scan over M = R*N ints (2048 items / block) ----
__global__ void scan1(const int* __restrict__ cnt, int* __restrict__ off,
                      int* __restrict__ part, int M) {
    __shared__ int sd[256];
    const int t = threadIdx.x, b = blockIdx.x;
    const int base = b * 2048 + t * 8;
    int v[8]; int tsum = 0;
    #pragma unroll
    for (int i = 0; i < 8; i++) { int g = base + i; v[i] = (g < M) ? cnt[g] : 0; tsum += v[i]; }
    sd[t] = tsum; __syncthreads();
    for (int d = 1; d < 256; d <<= 1) {
        int val = 0;
        if (t >= d) val = sd[t - d];
        __syncthreads();
        if (t >= d) sd[t] += val;
        __syncthreads();
    }
    int run = sd[t] - tsum;
    if (t == 255) part[b] = sd[255];
    #pragma unroll
    for (int i = 0; i < 8; i++) { int g = base + i; if (g < M) off[g] = run; run += v[i]; }
}

// Single block; requires nb <= 256 (R*N=400k -> nb=196).
__global__ void scan2(int* __restrict__ part, int nb, int* __restrict__ offM) {
    __shared__ int sd[256];
    const int t = threadIdx.x;
    int v = (t < nb) ? part[t] : 0;
    sd[t] = v; __syncthreads();
    for (int d = 1; d < 256; d <<= 1) {
        int val = 0;
        if (t >= d) val = sd[t - d];
        __syncthreads();
        if (t >= d) sd[t] += val;
        __syncthreads();
    }
    if (t < nb) part[t] = sd[t] - v;
    if (t == 255) *offM = sd[255];
}

__global__ void scan3(int* __restrict__ off, const int* __restrict__ part, int M) {
    const int add = part[blockIdx.x];
    const int base = blockIdx.x * 2048 + threadIdx.x;
    #pragma unroll
    for (int i = 0; i < 8; i++) { int g = base + i * 256; if (g < M) off[g] += add; }
}

// Scatter src ids into CSR slots; decrements cnt back to 0 (used as cursor).
__global__ void fill_csr(const int* __restrict__ src, const int* __restrict__ dst,
                         const int* __restrict__ off, int* __restrict__ cnt,
                         int* __restrict__ csr, int E, int N, int total) {
    int i = blockIdx.x * 256 + threadIdx.x;
    if (i >= total) return;
    int r = i / E;
    int idx = r * N + dst[i];
    int pos = atomicAdd(&cnt[idx], -1) - 1;
    csr[off[idx] + pos] = src[i];
}

// Block = 64 dst nodes. Per relation: edge-parallel gather into LDS fp32 tile
// (rotated slots -> ~2-way banks), normalize+cvt -> As bf16, MFMA-accumulate.
// Self-loop phase, then +bias/ReLU epilogue, single out write.
__global__ __launch_bounds__(256)
void fused(const float* __restrict__ x, const int* __restrict__ off,
           const int* __restrict__ csr, const unsigned short* __restrict__ Wt,
           const float* __restrict__ bias, float* __restrict__ out, int N) {
    __shared__ float aggF[64 * 128];          // 32 KB fp32 accumulator
    __shared__ unsigned short As[64 * 136];   // 17.4 KB bf16 A-tile (pad 8)
    __shared__ int offS[64];                  // global CSR start per node
    __shared__ int cumEx[65];                 // block-local exclusive edge cumsum

    const int t    = threadIdx.x;
    const int lane = t & 63;
    const int w    = t >> 6;
    const int n0   = blockIdx.x * 64;
    const int lr   = lane & 15;
    const int kg   = lane >> 4;
    const int myN  = t >> 2;            // node within tile (0..63)
    const int myC  = (t & 3) * 32;      // feature chunk base

    f32x4 acc[8];
    #pragma unroll
    for (int ct = 0; ct < 8; ct++) acc[ct] = (f32x4)(0.0f);

    for (int r = 0; r < 4; r++) {
        // zero the fp32 accumulator (all threads) + load ranges & scan (wave 0)
        {
            f4* az = (f4*)aggF;
            #pragma unroll
            for (int i = 0; i < 8; i++) az[t + i * 256] = (f4)(0.0f);
        }
        if (w == 0) {
            int n = n0 + lane;
            int o0 = 0, o1 = 0;
            if (n < N) { o0 = off[r * N + n]; o1 = off[r * N + n + 1]; }
            offS[lane] = o0;
            int run = o1 - o0;
            #pragma unroll
            for (int s2 = 1; s2 < 64; s2 <<= 1) {
                int v = __shfl_up(run, s2);
                if (lane >= s2) run += v;
            }
            cumEx[lane + 1] = run;
            if (lane == 0) cumEx[0] = 0;
        }
        __syncthreads();

        // edge-parallel gather: task = (edge, 32-feature chunk)
        const int T4 = cumEx[64] << 2;
        for (int j = t; j < T4; j += 256) {
            const int e = j >> 2, c = j & 3;
            int n = 0;
            #pragma unroll
            for (int s2 = 32; s2 > 0; s2 >>= 1)
                if (cumEx[n + s2] <= e) n += s2;
            const int srcn = csr[offS[n] + (e - cumEx[n])];
            const float* xr = x + (long long)srcn * DIN + c * 32;
            f4 v[8];
            #pragma unroll
            for (int q = 0; q < 8; q++) v[q] = *(const f4*)(xr + q * 4);
            const int rb = n + 8 * c;        // bank rotation base
            float* ab = aggF + n * 128 + c * 32;
            #pragma unroll
            for (int q = 0; q < 8; q++) {
                #pragma unroll
                for (int i2 = 0; i2 < 4; i2++) {
                    const int i = q * 4 + i2;
                    atomicAdd(ab + ((i + rb) & 31), v[q][i2]);
                }
            }
        }
        __syncthreads();

        // normalize + convert -> As (un-rotate)
        {
            const int deg = cumEx[myN + 1] - cumEx[myN];
            const float sc = 1.0f / fmaxf((float)deg, 1.0f);
            const int rb = myN + 8 * (t & 3);
            const float* ab = aggF + myN * 128 + myC;
            unsigned short* as = As + myN * 136 + myC;
            #pragma unroll
            for (int g = 0; g < 4; g++) {
                u16x8 p;
                #pragma unroll
                for (int i2 = 0; i2 < 8; i2++) {
                    const int i = g * 8 + i2;
                    p[i2] = f2bf(ab[(i + rb) & 31] * sc);
                }
                *(u16x8*)(as + g * 8) = p;
            }
        }
        __syncthreads();

        // MFMA-accumulate this relation
        const unsigned short* WtR = Wt + (r << 14);
        #pragma unroll
        for (int k0 = 0; k0 < DIN; k0 += 32) {
            bf16x8 a = *(const bf16x8*)&As[(w * 16 + lr) * 136 + k0 + kg * 8];
            #pragma unroll
            for (int ct = 0; ct < 8; ct++) {
                bf16x8 bfr = *(const bf16x8*)&WtR[((ct * 16 + lr) << 7) + k0 + kg * 8];
                acc[ct] = __builtin_amdgcn_mfma_f32_16x16x32_bf16(a, bfr, acc[ct], 0, 0, 0);
            }
        }
        __syncthreads();   // As readers done before next phase overwrites
    }

    // self-loop phase: A = x[node] directly
    {
        const int node = n0 + myN;
        const float* xr = x + (long long)(node < N ? node : 0) * DIN + myC;
        unsigned short* as = As + myN * 136 + myC;
        #pragma unroll
        for (int g = 0; g < 4; g++) {
            f4 v = *(const f4*)(xr + g * 8);
            f4 v2 = *(const f4*)(xr + g * 8 + 4);
            u16x8 p;
            p[0] = f2bf(v[0]);  p[1] = f2bf(v[1]);  p[2] = f2bf(v[2]);  p[3] = f2bf(v[3]);
            p[4] = f2bf(v2[0]); p[5] = f2bf(v2[1]); p[6] = f2bf(v2[2]); p[7] = f2bf(v2[3]);
            *(u16x8*)(as + g * 8) = p;
        }
    }
    __syncthreads();
    {
        const unsigned short* WtS = Wt + (4 << 14);
        #pragma unroll
        for (int k0 = 0; k0 < DIN; k0 += 32) {
            bf16x8 a = *(const bf16x8*)&As[(w * 16 + lr) * 136 + k0 + kg * 8];
            #pragma unroll
            for (int ct = 0; ct < 8; ct++) {
                bf16x8 bfr = *(const bf16x8*)&WtS[((ct * 16 + lr) << 7) + k0 + kg * 8];
                acc[ct] = __builtin_amdgcn_mfma_f32_16x16x32_bf16(a, bfr, acc[ct], 0, 0, 0);
            }
        }
    }

    // epilogue: +bias, ReLU, single write
    #pragma unroll
    for (int j = 0; j < 4; j++) {
        int n2 = n0 + w * 16 + kg * 4 + j;
        if (n2 >= N) continue;
        float* orow = out + (long long)n2 * DOUT + lr;
        #pragma unroll
        for (int ct = 0; ct < 8; ct++) {
            float v = acc[ct][j] + bias[ct * 16 + lr];
            orow[ct * 16] = fmaxf(v, 0.0f);
        }
    }
}

extern "C" void kernel_launch(void* const* d_in, const int* in_sizes, int n_in,
                              void* d_out, int out_size, void* d_ws, size_t ws_size,
                              hipStream_t stream) {
    const float* x  = (const float*)d_in[0];
    const float* W  = (const float*)d_in[1];
    const float* Wl = (const float*)d_in[2];
    const float* b  = (const float*)d_in[3];
    const int* src  = (const int*)d_in[4];
    const int* dst  = (const int*)d_in[5];
    float* out = (float*)d_out;

    const int N = in_sizes[0] / DIN;
    const int R = in_sizes[1] / (DIN * DOUT);
    const int E = in_sizes[4] / R;
    const int M = R * N;
    const int totE = R * E;

    // workspace layout
    unsigned short* Wt = (unsigned short*)d_ws;        // 5*16384 bf16 = 160 KB
    int* cnt  = (int*)((char*)d_ws + 5 * 16384 * 2);   // [M]
    int* off  = cnt + M;                               // [M+1]
    int* part = off + M + 1;                           // [256]
    int* csr  = part + 256;                            // [R*E]

    hipMemsetAsync(cnt, 0, (size_t)M * sizeof(int), stream);

    prep_w<<<(5 * DIN * DOUT + 255) / 256, 256, 0, stream>>>(W, Wl, Wt, 5 * DIN * DOUT);

    deg_count<<<(totE + 255) / 256, 256, 0, stream>>>(dst, cnt, E, N, totE);

    const int nb = (M + 2047) / 2048;                  // 196 for R*N = 400k
    scan1<<<nb, 256, 0, stream>>>(cnt, off, part, M);
    scan2<<<1, 256, 0, stream>>>(part, nb, off + M);
    scan3<<<nb, 256, 0, stream>>>(off, part, M);

    fill_csr<<<(totE + 255) / 256, 256, 0, stream>>>(src, dst, off, cnt, csr, E, N, totE);

    fused<<<(N + 63) / 64, 256, 0, stream>>>(x, off, csr, Wt, b, out, N);
}

// Round 9
// 341.966 us; speedup vs baseline: 1.9204x; 1.9204x over previous
//
#include <hip/hip_runtime.h>

#define DIN 128
#define DOUT 128

typedef float f4 __attribute__((ext_vector_type(4)));
typedef float f32x4 __attribute__((ext_vector_type(4)));
typedef short bf16x8 __attribute__((ext_vector_type(8)));
typedef unsigned short u16x8 __attribute__((ext_vector_type(8)));
typedef unsigned short u16x4 __attribute__((ext_vector_type(4)));

__device__ inline unsigned short f2bf(float f) {
    unsigned u = __float_as_uint(f);
    u += 0x7FFFu + ((u >> 16) & 1u);   // round-to-nearest-even
    return (unsigned short)(u >> 16);
}

// Build Wt[m][dout][din] bf16 from W[r][din][dout] (m=0..3) and Wl[din][dout] (m=4).
__global__ void prep_w(const float* __restrict__ W, const float* __restrict__ Wl,
                       unsigned short* __restrict__ Wt, int total) {
    int id = blockIdx.x * 256 + threadIdx.x;
    if (id >= total) return;
    int m    = id >> 14;
    int rem  = id & 16383;
    int din  = rem >> 7;
    int dout = rem & 127;
    float v = (m < 4) ? W[(m << 14) + din * DOUT + dout] : Wl[din * DOUT + dout];
    Wt[(m << 14) + dout * DIN + din] = f2bf(v);
}

__global__ void deg_count(const int* __restrict__ dst, int* __restrict__ cnt,
                          int E, int N, int total) {
    int i = blockIdx.x * 256 + threadIdx.x;
    if (i >= total) return;
    int r = i / E;
    atomicAdd(&cnt[r * N + dst[i]], 1);
}

// ---- 3-pass exclusive scan over M = R*N ints (2048 items / block) ----
__global__ void scan1(const int* __restrict__ cnt, int* __restrict__ off,
                      int* __restrict__ part, int M) {
    __shared__ int sd[256];
    const int t = threadIdx.x, b = blockIdx.x;
    const int base = b * 2048 + t * 8;
    int v[8]; int tsum = 0;
    #pragma unroll
    for (int i = 0; i < 8; i++) { int g = base + i; v[i] = (g < M) ? cnt[g] : 0; tsum += v[i]; }
    sd[t] = tsum; __syncthreads();
    for (int d = 1; d < 256; d <<= 1) {
        int val = 0;
        if (t >= d) val = sd[t - d];
        __syncthreads();
        if (t >= d) sd[t] += val;
        __syncthreads();
    }
    int run = sd[t] - tsum;
    if (t == 255) part[b] = sd[255];
    #pragma unroll
    for (int i = 0; i < 8; i++) { int g = base + i; if (g < M) off[g] = run; run += v[i]; }
}

// Single block; requires nb <= 256 (R*N=400k -> nb=196).
__global__ void scan2(int* __restrict__ part, int nb, int* __restrict__ offM) {
    __shared__ int sd[256];
    const int t = threadIdx.x;
    int v = (t < nb) ? part[t] : 0;
    sd[t] = v; __syncthreads();
    for (int d = 1; d < 256; d <<= 1) {
        int val = 0;
        if (t >= d) val = sd[t - d];
        __syncthreads();
        if (t >= d) sd[t] += val;
        __syncthreads();
    }
    if (t < nb) part[t] = sd[t] - v;
    if (t == 255) *offM = sd[255];
}

__global__ void scan3(int* __restrict__ off, const int* __restrict__ part, int M) {
    const int add = part[blockIdx.x];
    const int base = blockIdx.x * 2048 + threadIdx.x;
    #pragma unroll
    for (int i = 0; i < 8; i++) { int g = base + i * 256; if (g < M) off[g] += add; }
}

// Scatter src ids into CSR slots; decrements cnt back to 0 (used as cursor).
__global__ void fill_csr(const int* __restrict__ src, const int* __restrict__ dst,
                         const int* __restrict__ off, int* __restrict__ cnt,
                         int* __restrict__ csr, int E, int N, int total) {
    int i = blockIdx.x * 256 + threadIdx.x;
    if (i >= total) return;
    int r = i / E;
    int idx = r * N + dst[i];
    int pos = atomicAdd(&cnt[idx], -1) - 1;
    csr[off[idx] + pos] = src[i];
}

// Barrier-free gather: thread = (rel, node, f4-chunk). 32 lanes cover one
// node row; each edge = broadcast csr load + coalesced 512B x-row load.
// Writes normalized bf16 agg[rr][n][128].
__global__ __launch_bounds__(256)
void gather(const float* __restrict__ x, const int* __restrict__ off,
            const int* __restrict__ csr, unsigned short* __restrict__ agg,
            int r0, int N, int total) {
    int tid = blockIdx.x * 256 + threadIdx.x;
    if (tid >= total) return;
    const int c  = tid & 31;
    const int nn = tid >> 5;
    const int n  = nn % N;
    const int rr = nn / N;

    const int idx = (r0 + rr) * N + n;
    const int s0 = off[idx];
    const int s1 = off[idx + 1];

    f4 acc = (f4)(0.0f);
    for (int e = s0; e < s1; e++) {
        const int s = csr[e];
        acc += *(const f4*)&x[(long long)s * DIN + c * 4];
    }
    const float sc = 1.0f / fmaxf((float)(s1 - s0), 1.0f);
    acc *= sc;

    u16x4 p;
    p[0] = f2bf(acc[0]); p[1] = f2bf(acc[1]);
    p[2] = f2bf(acc[2]); p[3] = f2bf(acc[3]);
    *(u16x4*)&agg[((long long)rr * N + n) * DIN + c * 4] = p;
}

// Streaming GEMM: block = 64 nodes. For each of nRel relations: stage bf16
// agg tile -> padded LDS, MFMA-accumulate. Optionally self-loop (x cvt) +
// bias + ReLU. Optionally accumulate into existing out.
__global__ __launch_bounds__(256)
void gemm_multi(const float* __restrict__ x, const unsigned short* __restrict__ agg,
                const unsigned short* __restrict__ Wt, const float* __restrict__ bias,
                float* __restrict__ out, int N, int relStart, int nRel,
                int doSelf, int accumulate) {
    __shared__ unsigned short As[64 * 136];   // 17.4 KB (pad 8 bf16 per row)

    const int t    = threadIdx.x;
    const int lane = t & 63;
    const int w    = t >> 6;
    const int n0   = blockIdx.x * 64;
    const int lr   = lane & 15;
    const int kg   = lane >> 4;

    f32x4 acc[8];
    #pragma unroll
    for (int ct = 0; ct < 8; ct++) acc[ct] = (f32x4)(0.0f);

    for (int rr = 0; rr < nRel; rr++) {
        __syncthreads();   // previous MFMA done reading As
        // stage 64x128 bf16 tile: 1024 pieces of 16B, 4 per thread
        const unsigned short* srcA = agg + ((long long)rr * N + n0) * DIN;
        #pragma unroll
        for (int p = 0; p < 4; p++) {
            const int li  = t + p * 256;
            const int row = li >> 4;
            const int pc  = li & 15;
            u16x8 v;
            if (n0 + row < N) v = *(const u16x8*)&srcA[row * DIN + pc * 8];
            else              { for (int q = 0; q < 8; q++) v[q] = 0; }
            *(u16x8*)&As[row * 136 + pc * 8] = v;
        }
        __syncthreads();

        const unsigned short* WtR = Wt + ((relStart + rr) << 14);
        #pragma unroll
        for (int k0 = 0; k0 < DIN; k0 += 32) {
            bf16x8 a = *(const bf16x8*)&As[(w * 16 + lr) * 136 + k0 + kg * 8];
            #pragma unroll
            for (int ct = 0; ct < 8; ct++) {
                bf16x8 bfr = *(const bf16x8*)&WtR[((ct * 16 + lr) << 7) + k0 + kg * 8];
                acc[ct] = __builtin_amdgcn_mfma_f32_16x16x32_bf16(a, bfr, acc[ct], 0, 0, 0);
            }
        }
    }

    if (doSelf) {
        __syncthreads();
        {
            const int myN  = t >> 2;
            const int myC  = (t & 3) * 32;
            const int node = n0 + myN;
            const float* xr = x + (long long)(node < N ? node : 0) * DIN + myC;
            unsigned short* as = As + myN * 136 + myC;
            #pragma unroll
            for (int g = 0; g < 4; g++) {
                f4 v  = *(const f4*)(xr + g * 8);
                f4 v2 = *(const f4*)(xr + g * 8 + 4);
                u16x8 p;
                p[0] = f2bf(v[0]);  p[1] = f2bf(v[1]);  p[2] = f2bf(v[2]);  p[3] = f2bf(v[3]);
                p[4] = f2bf(v2[0]); p[5] = f2bf(v2[1]); p[6] = f2bf(v2[2]); p[7] = f2bf(v2[3]);
                *(u16x8*)(as + g * 8) = p;
            }
        }
        __syncthreads();
        const unsigned short* WtS = Wt + (4 << 14);
        #pragma unroll
        for (int k0 = 0; k0 < DIN; k0 += 32) {
            bf16x8 a = *(const bf16x8*)&As[(w * 16 + lr) * 136 + k0 + kg * 8];
            #pragma unroll
            for (int ct = 0; ct < 8; ct++) {
                bf16x8 bfr = *(const bf16x8*)&WtS[((ct * 16 + lr) << 7) + k0 + kg * 8];
                acc[ct] = __builtin_amdgcn_mfma_f32_16x16x32_bf16(a, bfr, acc[ct], 0, 0, 0);
            }
        }
    }

    // epilogue
    #pragma unroll
    for (int j = 0; j < 4; j++) {
        int n2 = n0 + w * 16 + kg * 4 + j;
        if (n2 >= N) continue;
        float* orow = out + (long long)n2 * DOUT + lr;
        #pragma unroll
        for (int ct = 0; ct < 8; ct++) {
            float v = acc[ct][j];
            if (accumulate) v += orow[ct * 16];
            if (doSelf) {
                v += bias[ct * 16 + lr];
                v = fmaxf(v, 0.0f);
            }
            orow[ct * 16] = v;
        }
    }
}

extern "C" void kernel_launch(void* const* d_in, const int* in_sizes, int n_in,
                              void* d_out, int out_size, void* d_ws, size_t ws_size,
                              hipStream_t stream) {
    const float* x  = (const float*)d_in[0];
    const float* W  = (const float*)d_in[1];
    const float* Wl = (const float*)d_in[2];
    const float* b  = (const float*)d_in[3];
    const int* src  = (const int*)d_in[4];
    const int* dst  = (const int*)d_in[5];
    float* out = (float*)d_out;

    const int N = in_sizes[0] / DIN;
    const int R = in_sizes[1] / (DIN * DOUT);
    const int E = in_sizes[4] / R;
    const int M = R * N;
    const int totE = R * E;

    // workspace layout
    char* wsp = (char*)d_ws;
    unsigned short* Wt = (unsigned short*)wsp;          // 5*16384 bf16 = 160 KB
    int* cnt  = (int*)(wsp + 5 * 16384 * 2);            // [M]
    int* off  = cnt + M;                                // [M+1]
    int* part = off + M + 1;                            // [256]
    int* csr  = part + 256;                             // [totE]
    size_t preBytes = ((char*)(csr + totE) - wsp + 255) & ~(size_t)255;
    unsigned short* agg = (unsigned short*)(wsp + preBytes);
    const size_t aggBytes = (size_t)N * DIN * sizeof(unsigned short);
    const bool fullPath = ws_size >= preBytes + (size_t)R * aggBytes;

    hipMemsetAsync(cnt, 0, (size_t)M * sizeof(int), stream);

    prep_w<<<(5 * DIN * DOUT + 255) / 256, 256, 0, stream>>>(W, Wl, Wt, 5 * DIN * DOUT);

    deg_count<<<(totE + 255) / 256, 256, 0, stream>>>(dst, cnt, E, N, totE);

    const int nb = (M + 2047) / 2048;
    scan1<<<nb, 256, 0, stream>>>(cnt, off, part, M);
    scan2<<<1, 256, 0, stream>>>(part, nb, off + M);
    scan3<<<nb, 256, 0, stream>>>(off, part, M);

    fill_csr<<<(totE + 255) / 256, 256, 0, stream>>>(src, dst, off, cnt, csr, E, N, totE);

    const int gemmGrid = (N + 63) / 64;
    if (fullPath) {
        const int total = R * N * 32;
        gather<<<(total + 255) / 256, 256, 0, stream>>>(x, off, csr, agg, 0, N, total);
        gemm_multi<<<gemmGrid, 256, 0, stream>>>(x, agg, Wt, b, out, N,
                                                 0, R, /*doSelf=*/1, /*accumulate=*/0);
    } else {
        const int total = N * 32;
        for (int r = 0; r < R; r++) {
            gather<<<(total + 255) / 256, 256, 0, stream>>>(x, off, csr, agg, r, N, total);
            gemm_multi<<<gemmGrid, 256, 0, stream>>>(x, agg, Wt, b, out, N,
                                                     r, 1, /*doSelf=*/(r == R - 1),
                                                     /*accumulate=*/(r > 0));
        }
    }
}

// Round 10
// 303.988 us; speedup vs baseline: 2.1603x; 1.1249x over previous
//
#include <hip/hip_runtime.h>

#define DIN 128
#define DOUT 128

typedef float f4 __attribute__((ext_vector_type(4)));
typedef float f32x4 __attribute__((ext_vector_type(4)));
typedef short bf16x8 __attribute__((ext_vector_type(8)));
typedef unsigned short u16x8 __attribute__((ext_vector_type(8)));
typedef unsigned short u16x4 __attribute__((ext_vector_type(4)));

__device__ inline unsigned short f2bf(float f) {
    unsigned u = __float_as_uint(f);
    u += 0x7FFFu + ((u >> 16) & 1u);   // round-to-nearest-even
    return (unsigned short)(u >> 16);
}

// Build Wt[m][dout][din] bf16 from W[r][din][dout] (m=0..3) and Wl[din][dout] (m=4).
__global__ void prep_w(const float* __restrict__ W, const float* __restrict__ Wl,
                       unsigned short* __restrict__ Wt, int total) {
    int id = blockIdx.x * 256 + threadIdx.x;
    if (id >= total) return;
    int m    = id >> 14;
    int rem  = id & 16383;
    int din  = rem >> 7;
    int dout = rem & 127;
    float v = (m < 4) ? W[(m << 14) + din * DOUT + dout] : Wl[din * DOUT + dout];
    Wt[(m << 14) + dout * DIN + din] = f2bf(v);
}

__global__ void deg_count(const int* __restrict__ dst, int* __restrict__ cnt,
                          int E, int N, int total) {
    int i = blockIdx.x * 256 + threadIdx.x;
    if (i >= total) return;
    int r = i / E;
    atomicAdd(&cnt[r * N + dst[i]], 1);
}

// ---- 3-pass exclusive scan over M = R*N ints (2048 items / block) ----
__global__ void scan1(const int* __restrict__ cnt, int* __restrict__ off,
                      int* __restrict__ part, int M) {
    __shared__ int sd[256];
    const int t = threadIdx.x, b = blockIdx.x;
    const int base = b * 2048 + t * 8;
    int v[8]; int tsum = 0;
    #pragma unroll
    for (int i = 0; i < 8; i++) { int g = base + i; v[i] = (g < M) ? cnt[g] : 0; tsum += v[i]; }
    sd[t] = tsum; __syncthreads();
    for (int d = 1; d < 256; d <<= 1) {
        int val = 0;
        if (t >= d) val = sd[t - d];
        __syncthreads();
        if (t >= d) sd[t] += val;
        __syncthreads();
    }
    int run = sd[t] - tsum;
    if (t == 255) part[b] = sd[255];
    #pragma unroll
    for (int i = 0; i < 8; i++) { int g = base + i; if (g < M) off[g] = run; run += v[i]; }
}

// Single block; requires nb <= 256 (R*N=400k -> nb=196).
__global__ void scan2(int* __restrict__ part, int nb, int* __restrict__ offM) {
    __shared__ int sd[256];
    const int t = threadIdx.x;
    int v = (t < nb) ? part[t] : 0;
    sd[t] = v; __syncthreads();
    for (int d = 1; d < 256; d <<= 1) {
        int val = 0;
        if (t >= d) val = sd[t - d];
        __syncthreads();
        if (t >= d) sd[t] += val;
        __syncthreads();
    }
    if (t < nb) part[t] = sd[t] - v;
    if (t == 255) *offM = sd[255];
}

__global__ void scan3(int* __restrict__ off, const int* __restrict__ part, int M) {
    const int add = part[blockIdx.x];
    const int base = blockIdx.x * 2048 + threadIdx.x;
    #pragma unroll
    for (int i = 0; i < 8; i++) { int g = base + i * 256; if (g < M) off[g] += add; }
}

// Scatter src ids into CSR slots; decrements cnt back to 0 (used as cursor).
__global__ void fill_csr(const int* __restrict__ src, const int* __restrict__ dst,
                         const int* __restrict__ off, int* __restrict__ cnt,
                         int* __restrict__ csr, int E, int N, int total) {
    int i = blockIdx.x * 256 + threadIdx.x;
    if (i >= total) return;
    int r = i / E;
    int idx = r * N + dst[i];
    int pos = atomicAdd(&cnt[idx], -1) - 1;
    csr[off[idx] + pos] = src[i];
}

// Barrier-free gather: thread = (rel, node, f4-chunk). 32 lanes cover one
// node row; each edge = broadcast csr load + coalesced 512B x-row load.
// Writes normalized bf16 agg[rr][n][128].
__global__ __launch_bounds__(256)
void gather(const float* __restrict__ x, const int* __restrict__ off,
            const int* __restrict__ csr, unsigned short* __restrict__ agg,
            int r0, int N, int total) {
    int tid = blockIdx.x * 256 + threadIdx.x;
    if (tid >= total) return;
    const int c  = tid & 31;
    const int nn = tid >> 5;
    const int n  = nn % N;
    const int rr = nn / N;

    const int idx = (r0 + rr) * N + n;
    const int s0 = off[idx];
    const int s1 = off[idx + 1];

    f4 acc = (f4)(0.0f);
    for (int e = s0; e < s1; e++) {
        const int s = csr[e];
        acc += *(const f4*)&x[(long long)s * DIN + c * 4];
    }
    const float sc = 1.0f / fmaxf((float)(s1 - s0), 1.0f);
    acc *= sc;

    u16x4 p;
    p[0] = f2bf(acc[0]); p[1] = f2bf(acc[1]);
    p[2] = f2bf(acc[2]); p[3] = f2bf(acc[3]);
    *(u16x4*)&agg[((long long)rr * N + n) * DIN + c * 4] = p;
}

// Zero-LDS, zero-barrier GEMM: MFMA fragments loaded directly from global.
// Block = 64 nodes (4 waves x 16 rows). A-frag: wave reads contiguous 4KB of
// agg (16 rows x 256B, 16B/lane). B-frag: Wt rows, L1/L2-resident. Tail rows
// clamped on load (A-row==C-row in GEMM, so garbage rows only feed guarded
// stores). Optional self-loop (x cvt in regs) + bias + ReLU + accumulate.
__global__ __launch_bounds__(256, 4)
void gemm_direct(const float* __restrict__ x, const unsigned short* __restrict__ agg,
                 const unsigned short* __restrict__ Wt, const float* __restrict__ bias,
                 float* __restrict__ out, int N, int relStart, int nRel,
                 int doSelf, int accumulate) {
    const int t    = threadIdx.x;
    const int lane = t & 63;
    const int w    = t >> 6;
    const int n0   = blockIdx.x * 64;
    const int lr   = lane & 15;
    const int kg   = lane >> 4;

    const int rowA = n0 + w * 16 + lr;
    const int rowC = (rowA < N) ? rowA : (N - 1);   // clamp tail

    f32x4 acc[8];
    #pragma unroll
    for (int ct = 0; ct < 8; ct++) acc[ct] = (f32x4)(0.0f);

    for (int rr = 0; rr < nRel; rr++) {
        const unsigned short* aggR = agg + ((long long)rr * N + rowC) * DIN;
        const unsigned short* WtR  = Wt + ((long long)(relStart + rr) << 14);
        #pragma unroll
        for (int k0 = 0; k0 < DIN; k0 += 32) {
            bf16x8 a = *(const bf16x8*)&aggR[k0 + kg * 8];
            #pragma unroll
            for (int ct = 0; ct < 8; ct++) {
                bf16x8 bfr = *(const bf16x8*)&WtR[((ct * 16 + lr) << 7) + k0 + kg * 8];
                acc[ct] = __builtin_amdgcn_mfma_f32_16x16x32_bf16(a, bfr, acc[ct], 0, 0, 0);
            }
        }
    }

    if (doSelf) {
        const float* xr = x + (long long)rowC * DIN;
        const unsigned short* WtS = Wt + ((long long)4 << 14);
        #pragma unroll
        for (int k0 = 0; k0 < DIN; k0 += 32) {
            f4 v  = *(const f4*)(xr + k0 + kg * 8);
            f4 v2 = *(const f4*)(xr + k0 + kg * 8 + 4);
            bf16x8 a;
            a[0] = (short)f2bf(v[0]);  a[1] = (short)f2bf(v[1]);
            a[2] = (short)f2bf(v[2]);  a[3] = (short)f2bf(v[3]);
            a[4] = (short)f2bf(v2[0]); a[5] = (short)f2bf(v2[1]);
            a[6] = (short)f2bf(v2[2]); a[7] = (short)f2bf(v2[3]);
            #pragma unroll
            for (int ct = 0; ct < 8; ct++) {
                bf16x8 bfr = *(const bf16x8*)&WtS[((ct * 16 + lr) << 7) + k0 + kg * 8];
                acc[ct] = __builtin_amdgcn_mfma_f32_16x16x32_bf16(a, bfr, acc[ct], 0, 0, 0);
            }
        }
    }

    // epilogue: D[m][n] -> n = lane&15 (dout), m = kg*4 + j (node row)
    #pragma unroll
    for (int j = 0; j < 4; j++) {
        int n2 = n0 + w * 16 + kg * 4 + j;
        if (n2 >= N) continue;
        float* orow = out + (long long)n2 * DOUT + lr;
        #pragma unroll
        for (int ct = 0; ct < 8; ct++) {
            float v = acc[ct][j];
            if (accumulate) v += orow[ct * 16];
            if (doSelf) {
                v += bias[ct * 16 + lr];
                v = fmaxf(v, 0.0f);
            }
            orow[ct * 16] = v;
        }
    }
}

extern "C" void kernel_launch(void* const* d_in, const int* in_sizes, int n_in,
                              void* d_out, int out_size, void* d_ws, size_t ws_size,
                              hipStream_t stream) {
    const float* x  = (const float*)d_in[0];
    const float* W  = (const float*)d_in[1];
    const float* Wl = (const float*)d_in[2];
    const float* b  = (const float*)d_in[3];
    const int* src  = (const int*)d_in[4];
    const int* dst  = (const int*)d_in[5];
    float* out = (float*)d_out;

    const int N = in_sizes[0] / DIN;
    const int R = in_sizes[1] / (DIN * DOUT);
    const int E = in_sizes[4] / R;
    const int M = R * N;
    const int totE = R * E;

    // workspace layout
    char* wsp = (char*)d_ws;
    unsigned short* Wt = (unsigned short*)wsp;          // 5*16384 bf16 = 160 KB
    int* cnt  = (int*)(wsp + 5 * 16384 * 2);            // [M]
    int* off  = cnt + M;                                // [M+1]
    int* part = off + M + 1;                            // [256]
    int* csr  = part + 256;                             // [totE]
    size_t preBytes = ((char*)(csr + totE) - wsp + 255) & ~(size_t)255;
    unsigned short* agg = (unsigned short*)(wsp + preBytes);
    const size_t aggBytes = (size_t)N * DIN * sizeof(unsigned short);
    const bool fullPath = ws_size >= preBytes + (size_t)R * aggBytes;

    hipMemsetAsync(cnt, 0, (size_t)M * sizeof(int), stream);

    prep_w<<<(5 * DIN * DOUT + 255) / 256, 256, 0, stream>>>(W, Wl, Wt, 5 * DIN * DOUT);

    deg_count<<<(totE + 255) / 256, 256, 0, stream>>>(dst, cnt, E, N, totE);

    const int nb = (M + 2047) / 2048;
    scan1<<<nb, 256, 0, stream>>>(cnt, off, part, M);
    scan2<<<1, 256, 0, stream>>>(part, nb, off + M);
    scan3<<<nb, 256, 0, stream>>>(off, part, M);

    fill_csr<<<(totE + 255) / 256, 256, 0, stream>>>(src, dst, off, cnt, csr, E, N, totE);

    const int gemmGrid = (N + 63) / 64;
    if (fullPath) {
        const int total = R * N * 32;
        gather<<<(total + 255) / 256, 256, 0, stream>>>(x, off, csr, agg, 0, N, total);
        gemm_direct<<<gemmGrid, 256, 0, stream>>>(x, agg, Wt, b, out, N,
                                                  0, R, /*doSelf=*/1, /*accumulate=*/0);
    } else {
        const int total = N * 32;
        for (int r = 0; r < R; r++) {
            gather<<<(total + 255) / 256, 256, 0, stream>>>(x, off, csr, agg, r, N, total);
            gemm_direct<<<gemmGrid, 256, 0, stream>>>(x, agg, Wt, b, out, N,
                                                      r, 1, /*doSelf=*/(r == R - 1),
                                                      /*accumulate=*/(r > 0));
        }
    }
}

// Round 11
// 202.748 us; speedup vs baseline: 3.2390x; 1.4993x over previous
//
#include <hip/hip_runtime.h>

#define DIN 128
#define DOUT 128

typedef float f4 __attribute__((ext_vector_type(4)));
typedef float f32x4 __attribute__((ext_vector_type(4)));
typedef short bf16x8 __attribute__((ext_vector_type(8)));
typedef unsigned short u16x8 __attribute__((ext_vector_type(8)));
typedef unsigned short u16x4 __attribute__((ext_vector_type(4)));

__device__ inline unsigned short f2bf(float f) {
    unsigned u = __float_as_uint(f);
    u += 0x7FFFu + ((u >> 16) & 1u);   // round-to-nearest-even
    return (unsigned short)(u >> 16);
}

// Build Wt[m][dout][din] bf16 from W[r][din][dout] (m=0..3) and Wl[din][dout] (m=4).
__global__ void prep_w(const float* __restrict__ W, const float* __restrict__ Wl,
                       unsigned short* __restrict__ Wt, int total) {
    int id = blockIdx.x * 256 + threadIdx.x;
    if (id >= total) return;
    int m    = id >> 14;
    int rem  = id & 16383;
    int din  = rem >> 7;
    int dout = rem & 127;
    float v = (m < 4) ? W[(m << 14) + din * DOUT + dout] : Wl[din * DOUT + dout];
    Wt[(m << 14) + dout * DIN + din] = f2bf(v);
}

__global__ void deg_count(const int* __restrict__ dst, int* __restrict__ cnt,
                          int E, int N, int total) {
    int i = blockIdx.x * 256 + threadIdx.x;
    if (i >= total) return;
    int r = i / E;
    atomicAdd(&cnt[r * N + dst[i]], 1);
}

// ---- 3-pass exclusive scan over M = R*N ints (2048 items / block) ----
__global__ void scan1(const int* __restrict__ cnt, int* __restrict__ off,
                      int* __restrict__ part, int M) {
    __shared__ int sd[256];
    const int t = threadIdx.x, b = blockIdx.x;
    const int base = b * 2048 + t * 8;
    int v[8]; int tsum = 0;
    #pragma unroll
    for (int i = 0; i < 8; i++) { int g = base + i; v[i] = (g < M) ? cnt[g] : 0; tsum += v[i]; }
    sd[t] = tsum; __syncthreads();
    for (int d = 1; d < 256; d <<= 1) {
        int val = 0;
        if (t >= d) val = sd[t - d];
        __syncthreads();
        if (t >= d) sd[t] += val;
        __syncthreads();
    }
    int run = sd[t] - tsum;
    if (t == 255) part[b] = sd[255];
    #pragma unroll
    for (int i = 0; i < 8; i++) { int g = base + i; if (g < M) off[g] = run; run += v[i]; }
}

// Single block; requires nb <= 256 (R*N=400k -> nb=196).
__global__ void scan2(int* __restrict__ part, int nb, int* __restrict__ offM) {
    __shared__ int sd[256];
    const int t = threadIdx.x;
    int v = (t < nb) ? part[t] : 0;
    sd[t] = v; __syncthreads();
    for (int d = 1; d < 256; d <<= 1) {
        int val = 0;
        if (t >= d) val = sd[t - d];
        __syncthreads();
        if (t >= d) sd[t] += val;
        __syncthreads();
    }
    if (t < nb) part[t] = sd[t] - v;
    if (t == 255) *offM = sd[255];
}

__global__ void scan3(int* __restrict__ off, const int* __restrict__ part, int M) {
    const int add = part[blockIdx.x];
    const int base = blockIdx.x * 2048 + threadIdx.x;
    #pragma unroll
    for (int i = 0; i < 8; i++) { int g = base + i * 256; if (g < M) off[g] += add; }
}

// Scatter src ids into CSR slots; decrements cnt back to 0 (used as cursor).
__global__ void fill_csr(const int* __restrict__ src, const int* __restrict__ dst,
                         const int* __restrict__ off, int* __restrict__ cnt,
                         int* __restrict__ csr, int E, int N, int total) {
    int i = blockIdx.x * 256 + threadIdx.x;
    if (i >= total) return;
    int r = i / E;
    int idx = r * N + dst[i];
    int pos = atomicAdd(&cnt[idx], -1) - 1;
    csr[off[idx] + pos] = src[i];
}

// Barrier-free gather: thread = (rel, node, f4-chunk). 32 lanes cover one
// node row; each edge = broadcast csr load + coalesced 512B x-row load.
// Writes normalized bf16 agg[rr][n][128].
__global__ __launch_bounds__(256)
void gather(const float* __restrict__ x, const int* __restrict__ off,
            const int* __restrict__ csr, unsigned short* __restrict__ agg,
            int r0, int N, int total) {
    int tid = blockIdx.x * 256 + threadIdx.x;
    if (tid >= total) return;
    const int c  = tid & 31;
    const int nn = tid >> 5;
    const int n  = nn % N;
    const int rr = nn / N;

    const int idx = (r0 + rr) * N + n;
    const int s0 = off[idx];
    const int s1 = off[idx + 1];

    f4 acc = (f4)(0.0f);
    for (int e = s0; e < s1; e++) {
        const int s = csr[e];
        acc += *(const f4*)&x[(long long)s * DIN + c * 4];
    }
    const float sc = 1.0f / fmaxf((float)(s1 - s0), 1.0f);
    acc *= sc;

    u16x4 p;
    p[0] = f2bf(acc[0]); p[1] = f2bf(acc[1]);
    p[2] = f2bf(acc[2]); p[3] = f2bf(acc[3]);
    *(u16x4*)&agg[((long long)rr * N + n) * DIN + c * 4] = p;
}

// GEMM with W staged per-relation into XOR-swizzled LDS (B-frag ds_read_b128
// conflict-free), A-frags prefetched into regs one relation ahead, self-loop
// x prefetched during rel 3. 2 barriers/relation; no per-MFMA global loads.
__global__ __launch_bounds__(256)
void gemm_lds(const float* __restrict__ x, const unsigned short* __restrict__ agg,
              const unsigned short* __restrict__ Wt, const float* __restrict__ bias,
              float* __restrict__ out, int N) {
    __shared__ unsigned short Ws[128 * 128];   // 32 KB, swizzled: slot ^= (row&7)

    const int t    = threadIdx.x;
    const int lane = t & 63;
    const int w    = t >> 6;
    const int n0   = blockIdx.x * 64;
    const int lr   = lane & 15;
    const int kg   = lane >> 4;
    const int lrm  = lr & 7;

    const int rowA = n0 + w * 16 + lr;
    const int rowC = (rowA < N) ? rowA : (N - 1);   // clamp tail (stores guarded)

    const long long relStride = (long long)N * DIN;

    f32x4 acc[8];
    #pragma unroll
    for (int ct = 0; ct < 8; ct++) acc[ct] = (f32x4)(0.0f);

    // prefetch A-frags for relation 0
    bf16x8 aCur[4], aNxt[4];
    {
        const unsigned short* a0 = agg + (long long)rowC * DIN;
        #pragma unroll
        for (int k = 0; k < 4; k++)
            aCur[k] = *(const bf16x8*)&a0[k * 32 + kg * 8];
    }

    f4 xlo[4], xhi[4];   // self-loop rows, prefetched during rel 3

    for (int r = 0; r < 4; r++) {
        // stage W_r -> LDS (swizzled), two reg-batches of 4x16B per thread
        {
            const unsigned short* Wg = Wt + ((long long)r << 14);
            #pragma unroll
            for (int h = 0; h < 2; h++) {
                u16x8 tmp[4];
                #pragma unroll
                for (int p = 0; p < 4; p++) {
                    const int li = t + (h * 4 + p) * 256;
                    tmp[p] = *(const u16x8*)&Wg[((li >> 4) << 7) + (li & 15) * 8];
                }
                #pragma unroll
                for (int p = 0; p < 4; p++) {
                    const int li  = t + (h * 4 + p) * 256;
                    const int row = li >> 4, cg = li & 15;
                    *(u16x8*)&Ws[(row << 7) + ((cg ^ (row & 7)) << 3)] = tmp[p];
                }
            }
        }
        // prefetch next relation's A-frags (or self-loop x on last rel)
        if (r < 3) {
            const unsigned short* an = agg + (r + 1) * relStride + (long long)rowC * DIN;
            #pragma unroll
            for (int k = 0; k < 4; k++)
                aNxt[k] = *(const bf16x8*)&an[k * 32 + kg * 8];
        } else {
            const float* xr = x + (long long)rowC * DIN;
            #pragma unroll
            for (int k = 0; k < 4; k++) {
                xlo[k] = *(const f4*)&xr[k * 32 + kg * 8];
                xhi[k] = *(const f4*)&xr[k * 32 + kg * 8 + 4];
            }
        }
        __syncthreads();   // W_r staged (drains all outstanding loads)

        #pragma unroll
        for (int k0i = 0; k0i < 4; k0i++) {
            #pragma unroll
            for (int ct = 0; ct < 8; ct++) {
                const int row  = ct * 16 + lr;
                const int slot = (k0i * 4 + kg) ^ lrm;
                bf16x8 b = *(const bf16x8*)&Ws[(row << 7) + (slot << 3)];
                acc[ct] = __builtin_amdgcn_mfma_f32_16x16x32_bf16(aCur[k0i], b, acc[ct], 0, 0, 0);
            }
        }
        #pragma unroll
        for (int k = 0; k < 4; k++) aCur[k] = aNxt[k];
        __syncthreads();   // all waves done reading Ws before restage
    }

    // self-loop: stage W4, convert prefetched x rows, MFMA
    {
        const unsigned short* Wg = Wt + ((long long)4 << 14);
        #pragma unroll
        for (int h = 0; h < 2; h++) {
            u16x8 tmp[4];
            #pragma unroll
            for (int p = 0; p < 4; p++) {
                const int li = t + (h * 4 + p) * 256;
                tmp[p] = *(const u16x8*)&Wg[((li >> 4) << 7) + (li & 15) * 8];
            }
            #pragma unroll
            for (int p = 0; p < 4; p++) {
                const int li  = t + (h * 4 + p) * 256;
                const int row = li >> 4, cg = li & 15;
                *(u16x8*)&Ws[(row << 7) + ((cg ^ (row & 7)) << 3)] = tmp[p];
            }
        }
        __syncthreads();

        #pragma unroll
        for (int k0i = 0; k0i < 4; k0i++) {
            bf16x8 a;
            a[0] = (short)f2bf(xlo[k0i][0]); a[1] = (short)f2bf(xlo[k0i][1]);
            a[2] = (short)f2bf(xlo[k0i][2]); a[3] = (short)f2bf(xlo[k0i][3]);
            a[4] = (short)f2bf(xhi[k0i][0]); a[5] = (short)f2bf(xhi[k0i][1]);
            a[6] = (short)f2bf(xhi[k0i][2]); a[7] = (short)f2bf(xhi[k0i][3]);
            #pragma unroll
            for (int ct = 0; ct < 8; ct++) {
                const int row  = ct * 16 + lr;
                const int slot = (k0i * 4 + kg) ^ lrm;
                bf16x8 b = *(const bf16x8*)&Ws[(row << 7) + (slot << 3)];
                acc[ct] = __builtin_amdgcn_mfma_f32_16x16x32_bf16(a, b, acc[ct], 0, 0, 0);
            }
        }
    }

    // epilogue: D[m][n] -> n = lane&15 (dout), m = kg*4 + j (node row)
    #pragma unroll
    for (int j = 0; j < 4; j++) {
        int n2 = n0 + w * 16 + kg * 4 + j;
        if (n2 >= N) continue;
        float* orow = out + (long long)n2 * DOUT + lr;
        #pragma unroll
        for (int ct = 0; ct < 8; ct++) {
            float v = acc[ct][j] + bias[ct * 16 + lr];
            orow[ct * 16] = fmaxf(v, 0.0f);
        }
    }
}

// Fallback (small ws): zero-LDS direct GEMM, per-relation accumulate.
__global__ __launch_bounds__(256, 4)
void gemm_direct(const float* __restrict__ x, const unsigned short* __restrict__ agg,
                 const unsigned short* __restrict__ Wt, const float* __restrict__ bias,
                 float* __restrict__ out, int N, int relStart, int nRel,
                 int doSelf, int accumulate) {
    const int t    = threadIdx.x;
    const int lane = t & 63;
    const int w    = t >> 6;
    const int n0   = blockIdx.x * 64;
    const int lr   = lane & 15;
    const int kg   = lane >> 4;

    const int rowA = n0 + w * 16 + lr;
    const int rowC = (rowA < N) ? rowA : (N - 1);

    f32x4 acc[8];
    #pragma unroll
    for (int ct = 0; ct < 8; ct++) acc[ct] = (f32x4)(0.0f);

    for (int rr = 0; rr < nRel; rr++) {
        const unsigned short* aggR = agg + ((long long)rr * N + rowC) * DIN;
        const unsigned short* WtR  = Wt + ((long long)(relStart + rr) << 14);
        #pragma unroll
        for (int k0 = 0; k0 < DIN; k0 += 32) {
            bf16x8 a = *(const bf16x8*)&aggR[k0 + kg * 8];
            #pragma unroll
            for (int ct = 0; ct < 8; ct++) {
                bf16x8 bfr = *(const bf16x8*)&WtR[((ct * 16 + lr) << 7) + k0 + kg * 8];
                acc[ct] = __builtin_amdgcn_mfma_f32_16x16x32_bf16(a, bfr, acc[ct], 0, 0, 0);
            }
        }
    }

    if (doSelf) {
        const float* xr = x + (long long)rowC * DIN;
        const unsigned short* WtS = Wt + ((long long)4 << 14);
        #pragma unroll
        for (int k0 = 0; k0 < DIN; k0 += 32) {
            f4 v  = *(const f4*)(xr + k0 + kg * 8);
            f4 v2 = *(const f4*)(xr + k0 + kg * 8 + 4);
            bf16x8 a;
            a[0] = (short)f2bf(v[0]);  a[1] = (short)f2bf(v[1]);
            a[2] = (short)f2bf(v[2]);  a[3] = (short)f2bf(v[3]);
            a[4] = (short)f2bf(v2[0]); a[5] = (short)f2bf(v2[1]);
            a[6] = (short)f2bf(v2[2]); a[7] = (short)f2bf(v2[3]);
            #pragma unroll
            for (int ct = 0; ct < 8; ct++) {
                bf16x8 bfr = *(const bf16x8*)&WtS[((ct * 16 + lr) << 7) + k0 + kg * 8];
                acc[ct] = __builtin_amdgcn_mfma_f32_16x16x32_bf16(a, bfr, acc[ct], 0, 0, 0);
            }
        }
    }

    #pragma unroll
    for (int j = 0; j < 4; j++) {
        int n2 = n0 + w * 16 + kg * 4 + j;
        if (n2 >= N) continue;
        float* orow = out + (long long)n2 * DOUT + lr;
        #pragma unroll
        for (int ct = 0; ct < 8; ct++) {
            float v = acc[ct][j];
            if (accumulate) v += orow[ct * 16];
            if (doSelf) {
                v += bias[ct * 16 + lr];
                v = fmaxf(v, 0.0f);
            }
            orow[ct * 16] = v;
        }
    }
}

extern "C" void kernel_launch(void* const* d_in, const int* in_sizes, int n_in,
                              void* d_out, int out_size, void* d_ws, size_t ws_size,
                              hipStream_t stream) {
    const float* x  = (const float*)d_in[0];
    const float* W  = (const float*)d_in[1];
    const float* Wl = (const float*)d_in[2];
    const float* b  = (const float*)d_in[3];
    const int* src  = (const int*)d_in[4];
    const int* dst  = (const int*)d_in[5];
    float* out = (float*)d_out;

    const int N = in_sizes[0] / DIN;
    const int R = in_sizes[1] / (DIN * DOUT);
    const int E = in_sizes[4] / R;
    const int M = R * N;
    const int totE = R * E;

    // workspace layout
    char* wsp = (char*)d_ws;
    unsigned short* Wt = (unsigned short*)wsp;          // 5*16384 bf16 = 160 KB
    int* cnt  = (int*)(wsp + 5 * 16384 * 2);            // [M]
    int* off  = cnt + M;                                // [M+1]
    int* part = off + M + 1;                            // [256]
    int* csr  = part + 256;                             // [totE]
    size_t preBytes = ((char*)(csr + totE) - wsp + 255) & ~(size_t)255;
    unsigned short* agg = (unsigned short*)(wsp + preBytes);
    const size_t aggBytes = (size_t)N * DIN * sizeof(unsigned short);
    const bool fullPath = (ws_size >= preBytes + (size_t)R * aggBytes) && (R == 4);

    hipMemsetAsync(cnt, 0, (size_t)M * sizeof(int), stream);

    prep_w<<<(5 * DIN * DOUT + 255) / 256, 256, 0, stream>>>(W, Wl, Wt, 5 * DIN * DOUT);

    deg_count<<<(totE + 255) / 256, 256, 0, stream>>>(dst, cnt, E, N, totE);

    const int nb = (M + 2047) / 2048;
    scan1<<<nb, 256, 0, stream>>>(cnt, off, part, M);
    scan2<<<1, 256, 0, stream>>>(part, nb, off + M);
    scan3<<<nb, 256, 0, stream>>>(off, part, M);

    fill_csr<<<(totE + 255) / 256, 256, 0, stream>>>(src, dst, off, cnt, csr, E, N, totE);

    const int gemmGrid = (N + 63) / 64;
    if (fullPath) {
        const int total = R * N * 32;
        gather<<<(total + 255) / 256, 256, 0, stream>>>(x, off, csr, agg, 0, N, total);
        gemm_lds<<<gemmGrid, 256, 0, stream>>>(x, agg, Wt, b, out, N);
    } else {
        const int total = N * 32;
        for (int r = 0; r < R; r++) {
            gather<<<(total + 255) / 256, 256, 0, stream>>>(x, off, csr, agg, r, N, total);
            gemm_direct<<<gemmGrid, 256, 0, stream>>>(x, agg, Wt, b, out, N,
                                                      r, 1, /*doSelf=*/(r == R - 1),
                                                      /*accumulate=*/(r > 0));
        }
    }
}